// Round 1
// baseline (590.503 us; speedup 1.0000x reference)
//
#include <hip/hip_runtime.h>

#define NN 50000
#define NE 800000
#define DDIM 64
#define PADX 68          // fp32 LDS row stride (node pool)
#define PADS 68          // fp32 per-wave scratch stride (rows are 272 B -> 16B aligned, odd*4 banks)
#define NB_SCAN ((NN + 255) / 256)   // 196
#define NEG_SLOPE 0.2f
#define EPS_V 1e-5f

typedef short bf16x8 __attribute__((ext_vector_type(8)));
typedef float f32x4 __attribute__((ext_vector_type(4)));

__device__ __forceinline__ float lrelu_f(float x) { return x >= 0.0f ? x : NEG_SLOPE * x; }

__device__ __forceinline__ unsigned short bf16_rn(float x) {
    union { float f; unsigned int u; } c; c.f = x;
    unsigned int r = c.u + 0x7FFF + ((c.u >> 16) & 1);
    return (unsigned short)(r >> 16);
}
__device__ __forceinline__ float bf16_tof(unsigned short h) {
    union { float f; unsigned int u; } c; c.u = ((unsigned int)h) << 16;
    return c.f;
}

// split 8 fp32 -> hi/lo bf16x8 (round-to-nearest both; ~2^-18 effective rel err)
__device__ __forceinline__ void split8(const float* __restrict__ v, bf16x8& h, bf16x8& l)
{
    #pragma unroll
    for (int j = 0; j < 8; ++j) {
        unsigned short hh = bf16_rn(v[j]);
        h[j] = (short)hh;
        l[j] = (short)bf16_rn(v[j] - bf16_tof(hh));
    }
}

// ---------------- fp32 micro-tile GEMM helpers (node pooling only) ----------------
__device__ __forceinline__ void mma_tile(float acc[16], const float* __restrict__ XT,
                                         const float* __restrict__ Wc, int e0, int f0)
{
    #pragma unroll 4
    for (int kk = 0; kk < DDIM; kk += 4) {
        float4 A0 = *(const float4*)&XT[(kk+0)*PADX + e0];
        float4 A1 = *(const float4*)&XT[(kk+1)*PADX + e0];
        float4 A2 = *(const float4*)&XT[(kk+2)*PADX + e0];
        float4 A3 = *(const float4*)&XT[(kk+3)*PADX + e0];
        float4 B0 = *(const float4*)&Wc[(f0+0)*PADX + kk];
        float4 B1 = *(const float4*)&Wc[(f0+1)*PADX + kk];
        float4 B2 = *(const float4*)&Wc[(f0+2)*PADX + kk];
        float4 B3 = *(const float4*)&Wc[(f0+3)*PADX + kk];
        const float a[4][4] = {{A0.x,A0.y,A0.z,A0.w},{A1.x,A1.y,A1.z,A1.w},
                               {A2.x,A2.y,A2.z,A2.w},{A3.x,A3.y,A3.z,A3.w}};
        const float b[4][4] = {{B0.x,B0.y,B0.z,B0.w},{B1.x,B1.y,B1.z,B1.w},
                               {B2.x,B2.y,B2.z,B2.w},{B3.x,B3.y,B3.z,B3.w}};
        #pragma unroll
        for (int j = 0; j < 4; ++j)
            #pragma unroll
            for (int i = 0; i < 4; ++i)
                #pragma unroll
                for (int q = 0; q < 4; ++q)
                    acc[i*4+j] = fmaf(a[q][i], b[j][q], acc[i*4+j]);
    }
}

__device__ __forceinline__ void load_w_f32(float* __restrict__ Wc, const float* __restrict__ Wg, int tid)
{
    #pragma unroll
    for (int c = 0; c < 4; ++c) {
        int idx = (c << 10) + (tid << 2);
        int f = idx >> 6, k = idx & 63;
        *(float4*)&Wc[f*PADX + k] = *(const float4*)&Wg[idx];
    }
}

// ---------------- node pooling (fp32) + fused dst histogram ----------------
__global__ __launch_bounds__(256, 3)
void node_pool_kernel(const float* __restrict__ V,
                      const float* __restrict__ Aw, const float* __restrict__ Ab,
                      const float* __restrict__ Bw, const float* __restrict__ Bbv,
                      float* __restrict__ Vp,
                      const int* __restrict__ dst, int* __restrict__ degi)
{
    __shared__ float Wc[DDIM*PADX];
    __shared__ float XT[DDIM*PADX];
    const int tid = threadIdx.x;
    const int nb = blockIdx.x * 64;
    const int e0 = (tid & 15) << 2;
    const int f0 = (tid >> 4) << 2;

    #pragma unroll
    for (int c = 0; c < 4; ++c) {
        int idx = (c << 10) + (tid << 2);
        int e = idx >> 6, d = idx & 63;
        int row = nb + e; if (row > NN-1) row = NN-1;
        float4 v = *(const float4*)&V[(size_t)row*DDIM + d];
        XT[(d+0)*PADX + e] = lrelu_f(v.x);
        XT[(d+1)*PADX + e] = lrelu_f(v.y);
        XT[(d+2)*PADX + e] = lrelu_f(v.z);
        XT[(d+3)*PADX + e] = lrelu_f(v.w);
    }
    load_w_f32(Wc, Aw, tid);
    __syncthreads();

    float acc[16];
    #pragma unroll
    for (int i = 0; i < 16; ++i) acc[i] = 0.f;
    mma_tile(acc, XT, Wc, e0, f0);
    __syncthreads();

    {   // lrelu(acc + Ab) -> XT
        float4 bv = *(const float4*)&Ab[f0];
        const float ba[4] = {bv.x, bv.y, bv.z, bv.w};
        #pragma unroll
        for (int j = 0; j < 4; ++j) {
            float4 v;
            v.x = lrelu_f(acc[0*4+j] + ba[j]);
            v.y = lrelu_f(acc[1*4+j] + ba[j]);
            v.z = lrelu_f(acc[2*4+j] + ba[j]);
            v.w = lrelu_f(acc[3*4+j] + ba[j]);
            *(float4*)&XT[(f0+j)*PADX + e0] = v;
        }
    }
    load_w_f32(Wc, Bw, tid);
    __syncthreads();

    float acc2[16];
    #pragma unroll
    for (int i = 0; i < 16; ++i) acc2[i] = 0.f;
    mma_tile(acc2, XT, Wc, e0, f0);

    float4 bv = *(const float4*)&Bbv[f0];
    #pragma unroll
    for (int i = 0; i < 4; ++i) {
        int row = nb + e0 + i;
        if (row < NN) {
            float4 o;
            o.x = acc2[i*4+0] + bv.x;
            o.y = acc2[i*4+1] + bv.y;
            o.z = acc2[i*4+2] + bv.z;
            o.w = acc2[i*4+3] + bv.w;
            *(float4*)&Vp[(size_t)row*DDIM + f0] = o;
        }
    }

    // fused histogram tail: grid-stride over edges
    const int stride = gridDim.x * 256;
    for (int e = blockIdx.x * 256 + tid; e < NE; e += stride)
        atomicAdd(&degi[dst[e]], 1);
}

// ---------------- split-bf16 weight fragment precompute ----------------
// Layout: WF[L][t][ks][hl][lane][j] shorts; per-layer stride 8192 shorts.
// lane: n=lane&15 (feature col), kg=lane>>4; f=t*16+n; k=ks*32+kg*8+j.
__global__ __launch_bounds__(256)
void prep_w_kernel(const float* __restrict__ W1, const float* __restrict__ W2,
                   const float* __restrict__ WB, const float* __restrict__ WC,
                   short* __restrict__ WF)
{
    int gid = blockIdx.x * 256 + threadIdx.x;   // grid = 64 blocks -> 16384 threads
    int L = gid >> 12, r = gid & 4095;
    int t = r >> 10, ks = (r >> 9) & 1, lane = (r >> 3) & 63, j = r & 7;
    const float* Ws = (L == 0) ? W1 : (L == 1) ? W2 : (L == 2) ? WB : WC;
    int n = lane & 15, kg = lane >> 4;
    int f = t*16 + n, k = ks*32 + kg*8 + j;
    float v = Ws[f*64 + k];
    unsigned short h = bf16_rn(v);
    unsigned short l = bf16_rn(v - bf16_tof(h));
    int base = L*8192 + ((t*2 + ks)*2)*512 + lane*8 + j;
    WF[base]       = (short)h;
    WF[base + 512] = (short)l;
}

// ---------------- CSR build: scan / scatter ----------------
__global__ __launch_bounds__(256)
void scan1_kernel(const int* __restrict__ degi, int* __restrict__ linc, int* __restrict__ bsum)
{
    __shared__ int ws[4];
    const int tid = threadIdx.x;
    const int lane = tid & 63, wv = tid >> 6;
    int i = blockIdx.x * 256 + tid;
    int v = (i < NN) ? degi[i] : 0;
    int sc = v;
    #pragma unroll
    for (int off = 1; off < 64; off <<= 1) {
        int t = __shfl_up(sc, off, 64);
        if (lane >= off) sc += t;
    }
    if (lane == 63) ws[wv] = sc;
    __syncthreads();
    int wb = 0;
    #pragma unroll
    for (int w = 0; w < 4; ++w) if (w < wv) wb += ws[w];
    int incl = sc + wb;
    if (i < NN) linc[i] = incl;
    if (tid == 255) bsum[blockIdx.x] = incl;
}

__global__ __launch_bounds__(256)
void scan23_kernel(const int* __restrict__ degi, const int* __restrict__ linc,
                   const int* __restrict__ bsum, int* __restrict__ curs)
{
    __shared__ int ws[4];
    __shared__ int base_s;
    const int tid = threadIdx.x;
    const int lane = tid & 63, wv = tid >> 6;
    int v = (tid < NB_SCAN) ? bsum[tid] : 0;
    int sc = v;
    #pragma unroll
    for (int off = 1; off < 64; off <<= 1) {
        int t = __shfl_up(sc, off, 64);
        if (lane >= off) sc += t;
    }
    if (lane == 63) ws[wv] = sc;
    __syncthreads();
    int wb = 0;
    #pragma unroll
    for (int w = 0; w < 4; ++w) if (w < wv) wb += ws[w];
    if (tid == blockIdx.x) base_s = sc + wb - v;
    __syncthreads();
    int i = blockIdx.x * 256 + tid;
    if (i < NN) curs[i] = base_s + linc[i] - degi[i];
}

__global__ __launch_bounds__(256)
void scatter_kernel(const int* __restrict__ dst, int* __restrict__ cursor, int* __restrict__ eidx)
{
    int e = blockIdx.x * 256 + threadIdx.x;
    if (e < NE) {
        int p = atomicAdd(&cursor[dst[e]], 1);
        eidx[p] = e;
    }
}

// ---------------- barrier-free per-wave split-bf16 MFMA edge kernel ----------------
// per-ks W fragment load: 8 frags (32 VGPRs)
__device__ __forceinline__ void gemm64(const short* __restrict__ WL, int lane,
                                       const bf16x8 ah[2], const bf16x8 al[2], f32x4 acc[4])
{
    #pragma unroll
    for (int ks = 0; ks < 2; ++ks) {
        bf16x8 bh[4], bl[4];
        #pragma unroll
        for (int t = 0; t < 4; ++t) {
            bh[t] = *(const bf16x8*)&WL[(((t*2 + ks)*2 + 0)*64 + lane)*8];
            bl[t] = *(const bf16x8*)&WL[(((t*2 + ks)*2 + 1)*64 + lane)*8];
        }
        #pragma unroll
        for (int t = 0; t < 4; ++t) {
            acc[t] = __builtin_amdgcn_mfma_f32_16x16x32_bf16(al[ks], bh[t], acc[t], 0, 0, 0);
            acc[t] = __builtin_amdgcn_mfma_f32_16x16x32_bf16(ah[ks], bl[t], acc[t], 0, 0, 0);
            acc[t] = __builtin_amdgcn_mfma_f32_16x16x32_bf16(ah[ks], bh[t], acc[t], 0, 0, 0);
        }
    }
}

// D-layout y[t][r] (f=t*16+n, e=mg*4+r) -> per-wave LDS -> A-frags for next layer.
// Wave-lockstep: DS ops from one wave complete in order; no __syncthreads needed.
__device__ __forceinline__ void transpose_frags(float* __restrict__ sw, const f32x4 y[4],
                                                int lane, bf16x8 ah[2], bf16x8 al[2])
{
    const int n = lane & 15, mg = lane >> 4;
    #pragma unroll
    for (int t = 0; t < 4; ++t)
        #pragma unroll
        for (int r = 0; r < 4; ++r)
            sw[(mg*4 + r)*PADS + t*16 + n] = y[t][r];
    __builtin_amdgcn_wave_barrier();
    const int m = lane & 15, kg = lane >> 4;   // m: edge row, kg: k-group
    float x[16];
    *(float4*)&x[0]  = *(const float4*)&sw[m*PADS + kg*8];
    *(float4*)&x[4]  = *(const float4*)&sw[m*PADS + kg*8 + 4];
    *(float4*)&x[8]  = *(const float4*)&sw[m*PADS + 32 + kg*8];
    *(float4*)&x[12] = *(const float4*)&sw[m*PADS + 32 + kg*8 + 4];
    split8(&x[0], ah[0], al[0]);
    split8(&x[8], ah[1], al[1]);
    __builtin_amdgcn_wave_barrier();
}

__global__ __launch_bounds__(256, 4)
void edge_kernel(const float* __restrict__ Eg,
                 const int* __restrict__ src, const int* __restrict__ dst,
                 const int* __restrict__ eidx,
                 const short* __restrict__ WF,
                 const float* __restrict__ b1, const float* __restrict__ b2,
                 const float* __restrict__ bB, const float* __restrict__ bC,
                 const float* __restrict__ Vp,
                 float* __restrict__ S1, float* __restrict__ S2)
{
    __shared__ float scratch[4 * 16 * PADS];   // per-wave 16x68 fp32 tiles (17408 B)
    __shared__ int aux[4 * 32];                // per-wave: [0..15]=src, [16..31]=dst

    const int tid = threadIdx.x;
    const int lane = tid & 63, wv = tid >> 6;
    float* sw = scratch + wv * 16 * PADS;
    int* auxw = aux + wv * 32;

    const int ew = blockIdx.x * 64 + wv * 16;  // this wave's 16 edges (dst-sorted)
    const int m = lane & 15, kg = lane >> 4;

    // stage: indices + E rows straight into A-fragments (no LDS)
    int eg = eidx[ew + m];
    if (lane < 16) {
        auxw[lane]      = src[eg];
        auxw[16 + lane] = dst[eg];
    }
    bf16x8 ah[2], al[2];
    {
        const float* er = Eg + (size_t)eg*DDIM + kg*8;
        float x[16];
        *(float4*)&x[0]  = *(const float4*)&er[0];
        *(float4*)&x[4]  = *(const float4*)&er[4];
        *(float4*)&x[8]  = *(const float4*)&er[32];
        *(float4*)&x[12] = *(const float4*)&er[36];
        split8(&x[0], ah[0], al[0]);
        split8(&x[8], ah[1], al[1]);
    }

    const int n = lane & 15, mg = lane >> 4;

    // layer 1
    f32x4 acc[4];
    #pragma unroll
    for (int t = 0; t < 4; ++t) acc[t] = (f32x4){0.f, 0.f, 0.f, 0.f};
    gemm64(WF, lane, ah, al, acc);
    #pragma unroll
    for (int t = 0; t < 4; ++t) {
        float b = b1[t*16 + n];
        #pragma unroll
        for (int r = 0; r < 4; ++r) acc[t][r] = fmaxf(acc[t][r] + b, 0.0f);
    }
    transpose_frags(sw, acc, lane, ah, al);

    // layer 2
    #pragma unroll
    for (int t = 0; t < 4; ++t) acc[t] = (f32x4){0.f, 0.f, 0.f, 0.f};
    gemm64(WF + 8192, lane, ah, al, acc);
    #pragma unroll
    for (int t = 0; t < 4; ++t) {
        float b = b2[t*16 + n];
        #pragma unroll
        for (int r = 0; r < 4; ++r) acc[t][r] = fmaxf(acc[t][r] + b, 0.0f);
    }
    transpose_frags(sw, acc, lane, ah, al);    // a-frags = x2

    // scale + shift heads (same A operand)
    f32x4 accS[4], accH[4];
    #pragma unroll
    for (int t = 0; t < 4; ++t) { accS[t] = (f32x4){0.f,0.f,0.f,0.f}; accH[t] = (f32x4){0.f,0.f,0.f,0.f}; }
    gemm64(WF + 2*8192, lane, ah, al, accS);
    gemm64(WF + 3*8192, lane, ah, al, accH);

    // message phase in D-layout registers: lane owns f=t*16+n, local edge e=mg*4+r
    {
        int sn[4];
        #pragma unroll
        for (int r = 0; r < 4; ++r) sn[r] = auxw[mg*4 + r];
        #pragma unroll
        for (int t = 0; t < 4; ++t) {
            const int f = t*16 + n;
            const float bBv = bB[f];
            const float bCv = bC[f];
            #pragma unroll
            for (int r = 0; r < 4; ++r) {
                float vp = Vp[(size_t)sn[r]*DDIM + f];
                float sg = 1.0f / (1.0f + __expf(-(accS[t][r] + bBv)));
                float m1 = fmaf(sg, vp, accH[t][r] + bCv);
                sw[(mg*4 + r)*PADS + f] = m1;
            }
        }
    }
    __builtin_amdgcn_wave_barrier();

    // per-wave segmented reduction: lane = feature (0..63), 16 dst-sorted edges
    const int f = lane;
    float s1 = 0.f, s2 = 0.f;
    int prev = auxw[16];
    #pragma unroll 4
    for (int e = 0; e < 16; ++e) {
        int dn = auxw[16 + e];
        float m1 = sw[e*PADS + f];
        float m2 = m1 * m1;
        if (dn != prev) {
            atomicAdd(&S1[(size_t)prev*DDIM + f], s1);
            atomicAdd(&S2[(size_t)prev*DDIM + f], s2);
            s1 = 0.f; s2 = 0.f; prev = dn;
        }
        s1 += m1; s2 += m2;
    }
    atomicAdd(&S1[(size_t)prev*DDIM + f], s1);
    atomicAdd(&S2[(size_t)prev*DDIM + f], s2);
}

// ---------------- finalize ----------------
__global__ __launch_bounds__(256)
void finalize_kernel(const float* __restrict__ S1, const float* __restrict__ S2,
                     const int* __restrict__ degi, float* __restrict__ out)
{
    int gid = blockIdx.x * blockDim.x + threadIdx.x;
    if (gid >= NN*DDIM) return;
    int n = gid >> 6;
    float dn = (float)degi[n];
    dn = dn > 1.0f ? dn : 1.0f;
    float v = (S2[gid] - S1[gid]) / dn;
    out[gid] = sqrtf(fmaxf(v, 0.0f) + EPS_V);
}

extern "C" void kernel_launch(void* const* d_in, const int* in_sizes, int n_in,
                              void* d_out, int out_size, void* d_ws, size_t ws_size,
                              hipStream_t stream) {
    const float* V   = (const float*)d_in[0];
    const float* Eg  = (const float*)d_in[1];
    const int*   src = (const int*)d_in[2];
    const int*   dst = (const int*)d_in[3];
    const float* pAw = (const float*)d_in[4];
    const float* pAb = (const float*)d_in[5];
    const float* pBw = (const float*)d_in[6];
    const float* pBb = (const float*)d_in[7];
    const float* mW1 = (const float*)d_in[8];
    const float* mb1 = (const float*)d_in[9];
    const float* mW2 = (const float*)d_in[10];
    const float* mb2 = (const float*)d_in[11];
    const float* BW  = (const float*)d_in[12];
    const float* Bb  = (const float*)d_in[13];
    const float* CW  = (const float*)d_in[14];
    const float* Cb  = (const float*)d_in[15];
    float* out = (float*)d_out;

    float* ws    = (float*)d_ws;
    float* Vp    = ws;                                   // NN*DDIM f32
    float* S1    = ws + (size_t)NN*DDIM;                 // NN*DDIM f32
    float* S2    = ws + (size_t)2*NN*DDIM;               // NN*DDIM f32
    int*   degi  = (int*)(ws + (size_t)3*NN*DDIM);       // NN i32
    int*   curs  = degi + NN;                            // NN i32
    int*   linc  = curs + NN;                            // NN i32
    int*   bsum  = linc + NN;                            // NB_SCAN i32
    int*   bbase = bsum + NB_SCAN;                       // NB_SCAN i32 (layout keep)
    int*   eidx  = bbase + NB_SCAN;                      // NE i32
    short* WF    = (short*)(eidx + NE);                  // 4*8192 shorts (64 KB)

    hipMemsetAsync(S1, 0, (size_t)(2*NN*DDIM + NN) * sizeof(float), stream);

    prep_w_kernel<<<64, 256, 0, stream>>>(mW1, mW2, BW, CW, WF);
    node_pool_kernel<<<(NN + 63)/64, 256, 0, stream>>>(V, pAw, pAb, pBw, pBb, Vp, dst, degi);
    scan1_kernel<<<NB_SCAN, 256, 0, stream>>>(degi, linc, bsum);
    scan23_kernel<<<NB_SCAN, 256, 0, stream>>>(degi, linc, bsum, curs);
    scatter_kernel<<<(NE + 255)/256, 256, 0, stream>>>(dst, curs, eidx);
    edge_kernel<<<NE/64, 256, 0, stream>>>(Eg, src, dst, eidx, WF,
                                           mb1, mb2, Bb, Cb, Vp, S1, S2);
    finalize_kernel<<<(NN*DDIM + 255)/256, 256, 0, stream>>>(S1, S2, degi, out);
}

// Round 2
// 577.682 us; speedup vs baseline: 1.0222x; 1.0222x over previous
//
#include <hip/hip_runtime.h>

#define NN 50000
#define NE 800000
#define DDIM 64
#define PADX 68          // fp32 LDS row stride (node pool)
#define PADS 68          // fp32 per-wave scratch stride (rows are 272 B -> 16B aligned, odd*4 banks)
#define NB_SCAN ((NN + 255) / 256)   // 196
#define NEG_SLOPE 0.2f
#define EPS_V 1e-5f

typedef short bf16x8 __attribute__((ext_vector_type(8)));
typedef float f32x4 __attribute__((ext_vector_type(4)));

__device__ __forceinline__ float lrelu_f(float x) { return x >= 0.0f ? x : NEG_SLOPE * x; }

__device__ __forceinline__ unsigned short bf16_rn(float x) {
    union { float f; unsigned int u; } c; c.f = x;
    unsigned int r = c.u + 0x7FFF + ((c.u >> 16) & 1);
    return (unsigned short)(r >> 16);
}
__device__ __forceinline__ float bf16_tof(unsigned short h) {
    union { float f; unsigned int u; } c; c.u = ((unsigned int)h) << 16;
    return c.f;
}

// split 8 fp32 -> hi/lo bf16x8 (round-to-nearest both; ~2^-18 effective rel err)
__device__ __forceinline__ void split8(const float* __restrict__ v, bf16x8& h, bf16x8& l)
{
    #pragma unroll
    for (int j = 0; j < 8; ++j) {
        unsigned short hh = bf16_rn(v[j]);
        h[j] = (short)hh;
        l[j] = (short)bf16_rn(v[j] - bf16_tof(hh));
    }
}

// ---------------- fp32 micro-tile GEMM helpers (node pooling only) ----------------
__device__ __forceinline__ void mma_tile(float acc[16], const float* __restrict__ XT,
                                         const float* __restrict__ Wc, int e0, int f0)
{
    #pragma unroll 4
    for (int kk = 0; kk < DDIM; kk += 4) {
        float4 A0 = *(const float4*)&XT[(kk+0)*PADX + e0];
        float4 A1 = *(const float4*)&XT[(kk+1)*PADX + e0];
        float4 A2 = *(const float4*)&XT[(kk+2)*PADX + e0];
        float4 A3 = *(const float4*)&XT[(kk+3)*PADX + e0];
        float4 B0 = *(const float4*)&Wc[(f0+0)*PADX + kk];
        float4 B1 = *(const float4*)&Wc[(f0+1)*PADX + kk];
        float4 B2 = *(const float4*)&Wc[(f0+2)*PADX + kk];
        float4 B3 = *(const float4*)&Wc[(f0+3)*PADX + kk];
        const float a[4][4] = {{A0.x,A0.y,A0.z,A0.w},{A1.x,A1.y,A1.z,A1.w},
                               {A2.x,A2.y,A2.z,A2.w},{A3.x,A3.y,A3.z,A3.w}};
        const float b[4][4] = {{B0.x,B0.y,B0.z,B0.w},{B1.x,B1.y,B1.z,B1.w},
                               {B2.x,B2.y,B2.z,B2.w},{B3.x,B3.y,B3.z,B3.w}};
        #pragma unroll
        for (int j = 0; j < 4; ++j)
            #pragma unroll
            for (int i = 0; i < 4; ++i)
                #pragma unroll
                for (int q = 0; q < 4; ++q)
                    acc[i*4+j] = fmaf(a[q][i], b[j][q], acc[i*4+j]);
    }
}

__device__ __forceinline__ void load_w_f32(float* __restrict__ Wc, const float* __restrict__ Wg, int tid)
{
    #pragma unroll
    for (int c = 0; c < 4; ++c) {
        int idx = (c << 10) + (tid << 2);
        int f = idx >> 6, k = idx & 63;
        *(float4*)&Wc[f*PADX + k] = *(const float4*)&Wg[idx];
    }
}

// ---------------- node pooling (fp32) + fused dst histogram ----------------
__global__ __launch_bounds__(256, 3)
void node_pool_kernel(const float* __restrict__ V,
                      const float* __restrict__ Aw, const float* __restrict__ Ab,
                      const float* __restrict__ Bw, const float* __restrict__ Bbv,
                      float* __restrict__ Vp,
                      const int* __restrict__ dst, int* __restrict__ degi)
{
    __shared__ float Wc[DDIM*PADX];
    __shared__ float XT[DDIM*PADX];
    const int tid = threadIdx.x;
    const int nb = blockIdx.x * 64;
    const int e0 = (tid & 15) << 2;
    const int f0 = (tid >> 4) << 2;

    #pragma unroll
    for (int c = 0; c < 4; ++c) {
        int idx = (c << 10) + (tid << 2);
        int e = idx >> 6, d = idx & 63;
        int row = nb + e; if (row > NN-1) row = NN-1;
        float4 v = *(const float4*)&V[(size_t)row*DDIM + d];
        XT[(d+0)*PADX + e] = lrelu_f(v.x);
        XT[(d+1)*PADX + e] = lrelu_f(v.y);
        XT[(d+2)*PADX + e] = lrelu_f(v.z);
        XT[(d+3)*PADX + e] = lrelu_f(v.w);
    }
    load_w_f32(Wc, Aw, tid);
    __syncthreads();

    float acc[16];
    #pragma unroll
    for (int i = 0; i < 16; ++i) acc[i] = 0.f;
    mma_tile(acc, XT, Wc, e0, f0);
    __syncthreads();

    {   // lrelu(acc + Ab) -> XT
        float4 bv = *(const float4*)&Ab[f0];
        const float ba[4] = {bv.x, bv.y, bv.z, bv.w};
        #pragma unroll
        for (int j = 0; j < 4; ++j) {
            float4 v;
            v.x = lrelu_f(acc[0*4+j] + ba[j]);
            v.y = lrelu_f(acc[1*4+j] + ba[j]);
            v.z = lrelu_f(acc[2*4+j] + ba[j]);
            v.w = lrelu_f(acc[3*4+j] + ba[j]);
            *(float4*)&XT[(f0+j)*PADX + e0] = v;
        }
    }
    load_w_f32(Wc, Bw, tid);
    __syncthreads();

    float acc2[16];
    #pragma unroll
    for (int i = 0; i < 16; ++i) acc2[i] = 0.f;
    mma_tile(acc2, XT, Wc, e0, f0);

    float4 bv = *(const float4*)&Bbv[f0];
    #pragma unroll
    for (int i = 0; i < 4; ++i) {
        int row = nb + e0 + i;
        if (row < NN) {
            float4 o;
            o.x = acc2[i*4+0] + bv.x;
            o.y = acc2[i*4+1] + bv.y;
            o.z = acc2[i*4+2] + bv.z;
            o.w = acc2[i*4+3] + bv.w;
            *(float4*)&Vp[(size_t)row*DDIM + f0] = o;
        }
    }

    // fused histogram tail: grid-stride over edges
    const int stride = gridDim.x * 256;
    for (int e = blockIdx.x * 256 + tid; e < NE; e += stride)
        atomicAdd(&degi[dst[e]], 1);
}

// ---------------- split-bf16 weight fragment precompute ----------------
// Layout: WF[L][t][ks][hl][lane][j] shorts; per-layer stride 8192 shorts.
// lane: n=lane&15 (feature col), kg=lane>>4; f=t*16+n; k=ks*32+kg*8+j.
__global__ __launch_bounds__(256)
void prep_w_kernel(const float* __restrict__ W1, const float* __restrict__ W2,
                   const float* __restrict__ WB, const float* __restrict__ WC,
                   short* __restrict__ WF)
{
    int gid = blockIdx.x * 256 + threadIdx.x;   // grid = 64 blocks -> 16384 threads
    int L = gid >> 12, r = gid & 4095;
    int t = r >> 10, ks = (r >> 9) & 1, lane = (r >> 3) & 63, j = r & 7;
    const float* Ws = (L == 0) ? W1 : (L == 1) ? W2 : (L == 2) ? WB : WC;
    int n = lane & 15, kg = lane >> 4;
    int f = t*16 + n, k = ks*32 + kg*8 + j;
    float v = Ws[f*64 + k];
    unsigned short h = bf16_rn(v);
    unsigned short l = bf16_rn(v - bf16_tof(h));
    int base = L*8192 + ((t*2 + ks)*2)*512 + lane*8 + j;
    WF[base]       = (short)h;
    WF[base + 512] = (short)l;
}

// ---------------- CSR build: scan / scatter ----------------
__global__ __launch_bounds__(256)
void scan1_kernel(const int* __restrict__ degi, int* __restrict__ linc, int* __restrict__ bsum)
{
    __shared__ int ws[4];
    const int tid = threadIdx.x;
    const int lane = tid & 63, wv = tid >> 6;
    int i = blockIdx.x * 256 + tid;
    int v = (i < NN) ? degi[i] : 0;
    int sc = v;
    #pragma unroll
    for (int off = 1; off < 64; off <<= 1) {
        int t = __shfl_up(sc, off, 64);
        if (lane >= off) sc += t;
    }
    if (lane == 63) ws[wv] = sc;
    __syncthreads();
    int wb = 0;
    #pragma unroll
    for (int w = 0; w < 4; ++w) if (w < wv) wb += ws[w];
    int incl = sc + wb;
    if (i < NN) linc[i] = incl;
    if (tid == 255) bsum[blockIdx.x] = incl;
}

__global__ __launch_bounds__(256)
void scan23_kernel(const int* __restrict__ degi, const int* __restrict__ linc,
                   const int* __restrict__ bsum, int* __restrict__ curs)
{
    __shared__ int ws[4];
    __shared__ int base_s;
    const int tid = threadIdx.x;
    const int lane = tid & 63, wv = tid >> 6;
    int v = (tid < NB_SCAN) ? bsum[tid] : 0;
    int sc = v;
    #pragma unroll
    for (int off = 1; off < 64; off <<= 1) {
        int t = __shfl_up(sc, off, 64);
        if (lane >= off) sc += t;
    }
    if (lane == 63) ws[wv] = sc;
    __syncthreads();
    int wb = 0;
    #pragma unroll
    for (int w = 0; w < 4; ++w) if (w < wv) wb += ws[w];
    if (tid == blockIdx.x) base_s = sc + wb - v;
    __syncthreads();
    int i = blockIdx.x * 256 + tid;
    if (i < NN) curs[i] = base_s + linc[i] - degi[i];
}

__global__ __launch_bounds__(256)
void scatter_kernel(const int* __restrict__ dst, int* __restrict__ cursor, int* __restrict__ eidx)
{
    int e = blockIdx.x * 256 + threadIdx.x;
    if (e < NE) {
        int p = atomicAdd(&cursor[dst[e]], 1);
        eidx[p] = e;
    }
}

// ---------------- barrier-free per-wave split-bf16 MFMA edge kernel ----------------
// Dual-tile GEMM: weight fragments loaded ONCE per (ks) serve both 16-row tiles.
__device__ __forceinline__ void gemm64_dual(const short* __restrict__ WL, int lane,
                                            const bf16x8 ah0[2], const bf16x8 al0[2],
                                            const bf16x8 ah1[2], const bf16x8 al1[2],
                                            f32x4 acc0[4], f32x4 acc1[4])
{
    #pragma unroll
    for (int ks = 0; ks < 2; ++ks) {
        bf16x8 bh[4], bl[4];
        #pragma unroll
        for (int t = 0; t < 4; ++t) {
            bh[t] = *(const bf16x8*)&WL[(((t*2 + ks)*2 + 0)*64 + lane)*8];
            bl[t] = *(const bf16x8*)&WL[(((t*2 + ks)*2 + 1)*64 + lane)*8];
        }
        #pragma unroll
        for (int t = 0; t < 4; ++t) {
            acc0[t] = __builtin_amdgcn_mfma_f32_16x16x32_bf16(al0[ks], bh[t], acc0[t], 0, 0, 0);
            acc1[t] = __builtin_amdgcn_mfma_f32_16x16x32_bf16(al1[ks], bh[t], acc1[t], 0, 0, 0);
            acc0[t] = __builtin_amdgcn_mfma_f32_16x16x32_bf16(ah0[ks], bl[t], acc0[t], 0, 0, 0);
            acc1[t] = __builtin_amdgcn_mfma_f32_16x16x32_bf16(ah1[ks], bl[t], acc1[t], 0, 0, 0);
            acc0[t] = __builtin_amdgcn_mfma_f32_16x16x32_bf16(ah0[ks], bh[t], acc0[t], 0, 0, 0);
            acc1[t] = __builtin_amdgcn_mfma_f32_16x16x32_bf16(ah1[ks], bh[t], acc1[t], 0, 0, 0);
        }
    }
}

// D-layout y[t][r] for both tiles -> per-wave 32-row LDS -> A-frags for next layer.
// Wave-lockstep: DS ops from one wave complete in order; no __syncthreads needed.
__device__ __forceinline__ void transpose_frags_dual(float* __restrict__ sw,
                                                     const f32x4 y0[4], const f32x4 y1[4],
                                                     int lane,
                                                     bf16x8 ah0[2], bf16x8 al0[2],
                                                     bf16x8 ah1[2], bf16x8 al1[2])
{
    const int n = lane & 15, mg = lane >> 4;
    #pragma unroll
    for (int t = 0; t < 4; ++t)
        #pragma unroll
        for (int r = 0; r < 4; ++r) {
            sw[(mg*4 + r)*PADS + t*16 + n]      = y0[t][r];
            sw[(16 + mg*4 + r)*PADS + t*16 + n] = y1[t][r];
        }
    __builtin_amdgcn_wave_barrier();
    const int m = lane & 15, kg = lane >> 4;   // m: edge row, kg: k-group
    {
        float x[16];
        *(float4*)&x[0]  = *(const float4*)&sw[m*PADS + kg*8];
        *(float4*)&x[4]  = *(const float4*)&sw[m*PADS + kg*8 + 4];
        *(float4*)&x[8]  = *(const float4*)&sw[m*PADS + 32 + kg*8];
        *(float4*)&x[12] = *(const float4*)&sw[m*PADS + 32 + kg*8 + 4];
        split8(&x[0], ah0[0], al0[0]);
        split8(&x[8], ah0[1], al0[1]);
    }
    {
        float x[16];
        *(float4*)&x[0]  = *(const float4*)&sw[(16+m)*PADS + kg*8];
        *(float4*)&x[4]  = *(const float4*)&sw[(16+m)*PADS + kg*8 + 4];
        *(float4*)&x[8]  = *(const float4*)&sw[(16+m)*PADS + 32 + kg*8];
        *(float4*)&x[12] = *(const float4*)&sw[(16+m)*PADS + 32 + kg*8 + 4];
        split8(&x[0], ah1[0], al1[0]);
        split8(&x[8], ah1[1], al1[1]);
    }
    __builtin_amdgcn_wave_barrier();
}

__global__ __launch_bounds__(256, 3)
void edge_kernel(const float* __restrict__ Eg,
                 const int* __restrict__ src, const int* __restrict__ dst,
                 const int* __restrict__ eidx,
                 const short* __restrict__ WF,
                 const float* __restrict__ b1, const float* __restrict__ b2,
                 const float* __restrict__ bB, const float* __restrict__ bC,
                 const float* __restrict__ Vp,
                 float* __restrict__ S1, float* __restrict__ S2)
{
    __shared__ float scratch[4 * 32 * PADS];   // per-wave 32x68 fp32 tiles (34816 B)
    __shared__ int aux[4 * 64];                // per-wave: [0..31]=src, [32..63]=dst

    const int tid = threadIdx.x;
    const int lane = tid & 63, wv = tid >> 6;
    float* sw = scratch + wv * 32 * PADS;
    int* auxw = aux + wv * 64;

    const int ew = blockIdx.x * 128 + wv * 32;  // this wave's 32 edges (dst-sorted)
    const int m = lane & 15, kg = lane >> 4;

    // stage: indices for all 32 edges
    if (lane < 32) {
        int eg = eidx[ew + lane];
        auxw[lane]      = src[eg];
        auxw[32 + lane] = dst[eg];
    }
    // A-fragments straight from gathered E rows (no LDS)
    bf16x8 ah0[2], al0[2], ah1[2], al1[2];
    {
        int eg0 = eidx[ew + m];
        int eg1 = eidx[ew + 16 + m];
        const float* er0 = Eg + (size_t)eg0*DDIM + kg*8;
        const float* er1 = Eg + (size_t)eg1*DDIM + kg*8;
        float x[16];
        *(float4*)&x[0]  = *(const float4*)&er0[0];
        *(float4*)&x[4]  = *(const float4*)&er0[4];
        *(float4*)&x[8]  = *(const float4*)&er0[32];
        *(float4*)&x[12] = *(const float4*)&er0[36];
        split8(&x[0], ah0[0], al0[0]);
        split8(&x[8], ah0[1], al0[1]);
        *(float4*)&x[0]  = *(const float4*)&er1[0];
        *(float4*)&x[4]  = *(const float4*)&er1[4];
        *(float4*)&x[8]  = *(const float4*)&er1[32];
        *(float4*)&x[12] = *(const float4*)&er1[36];
        split8(&x[0], ah1[0], al1[0]);
        split8(&x[8], ah1[1], al1[1]);
    }

    const int n = lane & 15, mg = lane >> 4;

    // layer 1
    f32x4 acc0[4], acc1[4];
    #pragma unroll
    for (int t = 0; t < 4; ++t) { acc0[t] = (f32x4){0.f,0.f,0.f,0.f}; acc1[t] = (f32x4){0.f,0.f,0.f,0.f}; }
    gemm64_dual(WF, lane, ah0, al0, ah1, al1, acc0, acc1);
    #pragma unroll
    for (int t = 0; t < 4; ++t) {
        float b = b1[t*16 + n];
        #pragma unroll
        for (int r = 0; r < 4; ++r) {
            acc0[t][r] = fmaxf(acc0[t][r] + b, 0.0f);
            acc1[t][r] = fmaxf(acc1[t][r] + b, 0.0f);
        }
    }
    transpose_frags_dual(sw, acc0, acc1, lane, ah0, al0, ah1, al1);

    // layer 2
    #pragma unroll
    for (int t = 0; t < 4; ++t) { acc0[t] = (f32x4){0.f,0.f,0.f,0.f}; acc1[t] = (f32x4){0.f,0.f,0.f,0.f}; }
    gemm64_dual(WF + 8192, lane, ah0, al0, ah1, al1, acc0, acc1);
    #pragma unroll
    for (int t = 0; t < 4; ++t) {
        float b = b2[t*16 + n];
        #pragma unroll
        for (int r = 0; r < 4; ++r) {
            acc0[t][r] = fmaxf(acc0[t][r] + b, 0.0f);
            acc1[t][r] = fmaxf(acc1[t][r] + b, 0.0f);
        }
    }
    transpose_frags_dual(sw, acc0, acc1, lane, ah0, al0, ah1, al1);   // a-frags = x2

    // scale + shift heads (same A operand, shared B-frags per head)
    f32x4 accS0[4], accS1[4], accH0[4], accH1[4];
    #pragma unroll
    for (int t = 0; t < 4; ++t) {
        accS0[t] = (f32x4){0.f,0.f,0.f,0.f}; accS1[t] = (f32x4){0.f,0.f,0.f,0.f};
        accH0[t] = (f32x4){0.f,0.f,0.f,0.f}; accH1[t] = (f32x4){0.f,0.f,0.f,0.f};
    }
    gemm64_dual(WF + 2*8192, lane, ah0, al0, ah1, al1, accS0, accS1);
    gemm64_dual(WF + 3*8192, lane, ah0, al0, ah1, al1, accH0, accH1);

    // message phase in D-layout registers: lane owns f=t*16+n, local edge e=(tile*16)+mg*4+r
    {
        int sn0[4], sn1[4];
        #pragma unroll
        for (int r = 0; r < 4; ++r) { sn0[r] = auxw[mg*4 + r]; sn1[r] = auxw[16 + mg*4 + r]; }
        #pragma unroll
        for (int t = 0; t < 4; ++t) {
            const int f = t*16 + n;
            const float bBv = bB[f];
            const float bCv = bC[f];
            #pragma unroll
            for (int r = 0; r < 4; ++r) {
                float vp0 = Vp[(size_t)sn0[r]*DDIM + f];
                float sg0 = 1.0f / (1.0f + __expf(-(accS0[t][r] + bBv)));
                sw[(mg*4 + r)*PADS + f] = fmaf(sg0, vp0, accH0[t][r] + bCv);
                float vp1 = Vp[(size_t)sn1[r]*DDIM + f];
                float sg1 = 1.0f / (1.0f + __expf(-(accS1[t][r] + bBv)));
                sw[(16 + mg*4 + r)*PADS + f] = fmaf(sg1, vp1, accH1[t][r] + bCv);
            }
        }
    }
    __builtin_amdgcn_wave_barrier();

    // per-wave segmented reduction: lane = feature (0..63), 32 dst-sorted edges
    const int f = lane;
    float s1 = 0.f, s2 = 0.f;
    int prev = auxw[32];
    #pragma unroll 4
    for (int e = 0; e < 32; ++e) {
        int dn = auxw[32 + e];
        float m1 = sw[e*PADS + f];
        float m2 = m1 * m1;
        if (dn != prev) {
            atomicAdd(&S1[(size_t)prev*DDIM + f], s1);
            atomicAdd(&S2[(size_t)prev*DDIM + f], s2);
            s1 = 0.f; s2 = 0.f; prev = dn;
        }
        s1 += m1; s2 += m2;
    }
    atomicAdd(&S1[(size_t)prev*DDIM + f], s1);
    atomicAdd(&S2[(size_t)prev*DDIM + f], s2);
}

// ---------------- finalize ----------------
__global__ __launch_bounds__(256)
void finalize_kernel(const float* __restrict__ S1, const float* __restrict__ S2,
                     const int* __restrict__ degi, float* __restrict__ out)
{
    int gid = blockIdx.x * blockDim.x + threadIdx.x;
    if (gid >= NN*DDIM) return;
    int n = gid >> 6;
    float dn = (float)degi[n];
    dn = dn > 1.0f ? dn : 1.0f;
    float v = (S2[gid] - S1[gid]) / dn;
    out[gid] = sqrtf(fmaxf(v, 0.0f) + EPS_V);
}

extern "C" void kernel_launch(void* const* d_in, const int* in_sizes, int n_in,
                              void* d_out, int out_size, void* d_ws, size_t ws_size,
                              hipStream_t stream) {
    const float* V   = (const float*)d_in[0];
    const float* Eg  = (const float*)d_in[1];
    const int*   src = (const int*)d_in[2];
    const int*   dst = (const int*)d_in[3];
    const float* pAw = (const float*)d_in[4];
    const float* pAb = (const float*)d_in[5];
    const float* pBw = (const float*)d_in[6];
    const float* pBb = (const float*)d_in[7];
    const float* mW1 = (const float*)d_in[8];
    const float* mb1 = (const float*)d_in[9];
    const float* mW2 = (const float*)d_in[10];
    const float* mb2 = (const float*)d_in[11];
    const float* BW  = (const float*)d_in[12];
    const float* Bb  = (const float*)d_in[13];
    const float* CW  = (const float*)d_in[14];
    const float* Cb  = (const float*)d_in[15];
    float* out = (float*)d_out;

    float* ws    = (float*)d_ws;
    float* Vp    = ws;                                   // NN*DDIM f32
    float* S1    = ws + (size_t)NN*DDIM;                 // NN*DDIM f32
    float* S2    = ws + (size_t)2*NN*DDIM;               // NN*DDIM f32
    int*   degi  = (int*)(ws + (size_t)3*NN*DDIM);       // NN i32
    int*   curs  = degi + NN;                            // NN i32
    int*   linc  = curs + NN;                            // NN i32
    int*   bsum  = linc + NN;                            // NB_SCAN i32
    int*   bbase = bsum + NB_SCAN;                       // NB_SCAN i32 (layout keep)
    int*   eidx  = bbase + NB_SCAN;                      // NE i32
    short* WF    = (short*)(eidx + NE);                  // 4*8192 shorts (64 KB)

    hipMemsetAsync(S1, 0, (size_t)(2*NN*DDIM + NN) * sizeof(float), stream);

    prep_w_kernel<<<64, 256, 0, stream>>>(mW1, mW2, BW, CW, WF);
    node_pool_kernel<<<(NN + 63)/64, 256, 0, stream>>>(V, pAw, pAb, pBw, pBb, Vp, dst, degi);
    scan1_kernel<<<NB_SCAN, 256, 0, stream>>>(degi, linc, bsum);
    scan23_kernel<<<NB_SCAN, 256, 0, stream>>>(degi, linc, bsum, curs);
    scatter_kernel<<<(NE + 255)/256, 256, 0, stream>>>(dst, curs, eidx);
    edge_kernel<<<NE/128, 256, 0, stream>>>(Eg, src, dst, eidx, WF,
                                            mb1, mb2, Bb, Cb, Vp, S1, S2);
    finalize_kernel<<<(NN*DDIM + 255)/256, 256, 0, stream>>>(S1, S2, degi, out);
}